// Round 1
// baseline (154.035 us; speedup 1.0000x reference)
//
#include <hip/hip_runtime.h>

#define DD 256
#define HH 4
#define RR 8
#define NW 4   // waves per block; one block per graph

// starts[g] = lower_bound(bi, g); starts[G] = N   (bi is sorted)
__global__ void starts_kernel(const int* __restrict__ bi, int* __restrict__ starts,
                              int N, int G) {
    int g = blockIdx.x * blockDim.x + threadIdx.x;
    if (g > G) return;
    int lo = 0, hi = N;
    while (lo < hi) { int mid = (lo + hi) >> 1; if (bi[mid] < g) lo = mid + 1; else hi = mid; }
    starts[g] = lo;
}

// one BLOCK per graph, 4 waves split the rows; flash-merge through LDS
__global__ __launch_bounds__(256) void fused_block(
    const float* __restrict__ x, const int* __restrict__ starts,
    const float* __restrict__ W, const float* __restrict__ b,
    const float* __restrict__ temp, float* __restrict__ scores_ws,
    float* __restrict__ xp, float* __restrict__ aw, int N, int G) {

    const int g    = blockIdx.x;
    const int lane = threadIdx.x & 63;
    const int wid  = threadIdx.x >> 6;

    const int s = starts[g];
    const int e = starts[g + 1];
    const int cnt = e - s;

    __shared__ float  ml_m[NW][HH];
    __shared__ float  ml_l[NW][HH];
    __shared__ float4 acc_lds[NW][HH][64];

    if (cnt == 0) {
        if (wid == 0)
            ((float4*)xp)[(size_t)g * 64 + lane] = make_float4(0.f, 0.f, 0.f, 0.f);
        return;
    }

    // this wave's contiguous row range [rs, re)  (may be empty for trailing waves)
    const int q   = (cnt + NW - 1) / NW;
    const int rs  = s + wid * q;
    const int re0 = rs + q;
    const int re  = re0 < e ? re0 : e;

    const float4* __restrict__ x4 = (const float4*)x;
    const float4* __restrict__ W4 = (const float4*)W;
    const float4 w0 = W4[0 * 64 + lane];
    const float4 w1 = W4[1 * 64 + lane];
    const float4 w2 = W4[2 * 64 + lane];
    const float4 w3 = W4[3 * 64 + lane];
    const float invT = 1.0f / temp[0];
    const float b0 = b[0], b1 = b[1], b2 = b[2], b3 = b[3];

    float m0 = -1e30f, m1 = -1e30f, m2 = -1e30f, m3 = -1e30f;
    float l0 = 0.f, l1 = 0.f, l2 = 0.f, l3 = 0.f;
    float4 a0 = make_float4(0.f,0.f,0.f,0.f), a1 = a0, a2 = a0, a3 = a0;

    for (int c = rs; c < re; c += RR) {
        const int cr = re - c;              // rows remaining (>= 1)
        float4 xv[RR];
        float pa[RR], pb[RR], pc[RR], pd[RR];

        #pragma unroll
        for (int j = 0; j < RR; ++j)
            if (j < cr) xv[j] = x4[(size_t)(c + j) * 64 + lane];

        #pragma unroll
        for (int j = 0; j < RR; ++j) {
            if (j < cr) {
                float q0 = xv[j].x*w0.x + xv[j].y*w0.y + xv[j].z*w0.z + xv[j].w*w0.w;
                float q1 = xv[j].x*w1.x + xv[j].y*w1.y + xv[j].z*w1.z + xv[j].w*w1.w;
                float q2 = xv[j].x*w2.x + xv[j].y*w2.y + xv[j].z*w2.z + xv[j].w*w2.w;
                float q3 = xv[j].x*w3.x + xv[j].y*w3.y + xv[j].z*w3.z + xv[j].w*w3.w;
                #pragma unroll
                for (int off = 32; off; off >>= 1) {
                    q0 += __shfl_xor(q0, off);
                    q1 += __shfl_xor(q1, off);
                    q2 += __shfl_xor(q2, off);
                    q3 += __shfl_xor(q3, off);
                }
                pa[j] = (q0 + b0) * invT;
                pb[j] = (q1 + b1) * invT;
                pc[j] = (q2 + b2) * invT;
                pd[j] = (q3 + b3) * invT;
            } else {
                pa[j] = -1e30f; pb[j] = -1e30f; pc[j] = -1e30f; pd[j] = -1e30f;
            }
        }

        // chunk max per head (values are lane-uniform)
        float c0 = pa[0], c1 = pb[0], c2 = pc[0], c3 = pd[0];
        #pragma unroll
        for (int j = 1; j < RR; ++j) {
            c0 = fmaxf(c0, pa[j]); c1 = fmaxf(c1, pb[j]);
            c2 = fmaxf(c2, pc[j]); c3 = fmaxf(c3, pd[j]);
        }
        const float n0 = fmaxf(m0, c0), n1 = fmaxf(m1, c1);
        const float n2 = fmaxf(m2, c2), n3 = fmaxf(m3, c3);
        const float s0 = __expf(m0 - n0), s1 = __expf(m1 - n1);
        const float s2 = __expf(m2 - n2), s3 = __expf(m3 - n3);
        a0.x *= s0; a0.y *= s0; a0.z *= s0; a0.w *= s0;  l0 *= s0;
        a1.x *= s1; a1.y *= s1; a1.z *= s1; a1.w *= s1;  l1 *= s1;
        a2.x *= s2; a2.y *= s2; a2.z *= s2; a2.w *= s2;  l2 *= s2;
        a3.x *= s3; a3.y *= s3; a3.z *= s3; a3.w *= s3;  l3 *= s3;
        m0 = n0; m1 = n1; m2 = n2; m3 = n3;

        #pragma unroll
        for (int j = 0; j < RR; ++j) {
            if (j < cr) {
                const float e0 = __expf(pa[j] - m0);
                const float e1 = __expf(pb[j] - m1);
                const float e2 = __expf(pc[j] - m2);
                const float e3 = __expf(pd[j] - m3);
                l0 += e0; l1 += e1; l2 += e2; l3 += e3;
                a0.x += e0*xv[j].x; a0.y += e0*xv[j].y; a0.z += e0*xv[j].z; a0.w += e0*xv[j].w;
                a1.x += e1*xv[j].x; a1.y += e1*xv[j].y; a1.z += e1*xv[j].z; a1.w += e1*xv[j].w;
                a2.x += e2*xv[j].x; a2.y += e2*xv[j].y; a2.z += e2*xv[j].z; a2.w += e2*xv[j].w;
                a3.x += e3*xv[j].x; a3.y += e3*xv[j].y; a3.z += e3*xv[j].z; a3.w += e3*xv[j].w;
                if (lane < HH) {
                    float v = (lane == 0) ? pa[j] : (lane == 1) ? pb[j]
                            : (lane == 2) ? pc[j] : pd[j];
                    scores_ws[(size_t)(c + j) * HH + lane] = v;
                }
            }
        }
    }

    // publish this wave's online-softmax state
    if (lane < HH) {
        const float mv = (lane == 0) ? m0 : (lane == 1) ? m1 : (lane == 2) ? m2 : m3;
        const float lv = (lane == 0) ? l0 : (lane == 1) ? l1 : (lane == 2) ? l2 : l3;
        ml_m[wid][lane] = mv;
        ml_l[wid][lane] = lv;
    }
    acc_lds[wid][0][lane] = a0;
    acc_lds[wid][1][lane] = a1;
    acc_lds[wid][2][lane] = a2;
    acc_lds[wid][3][lane] = a3;
    __syncthreads();

    // merged per-head running max / denom (every thread computes; LDS reads broadcast)
    float M[HH], L[HH];
    #pragma unroll
    for (int h = 0; h < HH; ++h) {
        float mm = ml_m[0][h];
        #pragma unroll
        for (int wv = 1; wv < NW; ++wv) mm = fmaxf(mm, ml_m[wv][h]);
        float ll = 0.f;
        #pragma unroll
        for (int wv = 0; wv < NW; ++wv) ll += ml_l[wv][h] * __expf(ml_m[wv][h] - mm);
        M[h] = mm; L[h] = ll;
    }

    // wave 0: merge accumulators and write pooled output (mean over heads)
    if (wid == 0) {
        float4 out = make_float4(0.f, 0.f, 0.f, 0.f);
        #pragma unroll
        for (int h = 0; h < HH; ++h) {
            const float il = 0.25f / L[h];
            #pragma unroll
            for (int wv = 0; wv < NW; ++wv) {
                const float f = __expf(ml_m[wv][h] - M[h]) * il;
                const float4 av = acc_lds[wv][h][lane];
                out.x += f * av.x; out.y += f * av.y;
                out.z += f * av.z; out.w += f * av.w;
            }
        }
        ((float4*)xp)[(size_t)g * 64 + lane] = out;
    }

    // attention weights [H, N] for this wave's own rows (reads back only OUR stores)
    const int nr = re - rs;
    if (nr > 0) {
        asm volatile("s_waitcnt vmcnt(0)" ::: "memory");
        const float il0 = 1.0f / L[0], il1 = 1.0f / L[1];
        const float il2 = 1.0f / L[2], il3 = 1.0f / L[3];
        const float M0 = M[0], M1 = M[1], M2 = M[2], M3 = M[3];
        for (int i = lane; i < nr; i += 64) {
            float4 sv = ((const float4*)scores_ws)[rs + i];
            aw[0 * (size_t)N + rs + i] = __expf(sv.x - M0) * il0;
            aw[1 * (size_t)N + rs + i] = __expf(sv.y - M1) * il1;
            aw[2 * (size_t)N + rs + i] = __expf(sv.z - M2) * il2;
            aw[3 * (size_t)N + rs + i] = __expf(sv.w - M3) * il3;
        }
    }
}

extern "C" void kernel_launch(void* const* d_in, const int* in_sizes, int n_in,
                              void* d_out, int out_size, void* d_ws, size_t ws_size,
                              hipStream_t stream) {
    const float* x    = (const float*)d_in[0];
    const int*   bi   = (const int*)d_in[1];
    // d_in[2] = num_graphs (derived from out_size)
    const float* W    = (const float*)d_in[3];
    const float* b    = (const float*)d_in[4];
    const float* temp = (const float*)d_in[5];

    const int N = in_sizes[0] / DD;
    const int G = (out_size - HH * N) / DD;

    float* xp = (float*)d_out;                    // [G, D]
    float* aw = (float*)d_out + (size_t)G * DD;   // [H, N]

    float* scores_ws = (float*)d_ws;                               // N*H floats
    int*   starts    = (int*)((char*)d_ws + (size_t)N * HH * 4);   // G+1 ints

    starts_kernel<<<(G + 1 + 255) / 256, 256, 0, stream>>>(bi, starts, N, G);
    fused_block<<<G, 256, 0, stream>>>(
        x, starts, W, b, temp, scores_ws, xp, aw, N, G);
}

// Round 2
// 88.784 us; speedup vs baseline: 1.7350x; 1.7350x over previous
//
#include <hip/hip_runtime.h>

#define DD 256
#define HH 4
#define NW 4   // waves per block; one GRAPH per wave

#define WAVE_LDS_FENCE() asm volatile("s_waitcnt lgkmcnt(0)" ::: "memory")
#define WAVE_VM_FENCE()  asm volatile("s_waitcnt vmcnt(0)" ::: "memory")

// starts[g] = lower_bound(bi, g); starts[G] = N   (bi is sorted)
__global__ void starts_kernel(const int* __restrict__ bi, int* __restrict__ starts,
                              int N, int G) {
    int g = blockIdx.x * blockDim.x + threadIdx.x;
    if (g > G) return;
    int lo = 0, hi = N;
    while (lo < hi) { int mid = (lo + hi) >> 1; if (bi[mid] < g) lo = mid + 1; else hi = mid; }
    starts[g] = lo;
}

// One wave per graph. Score phase: lane = row (no per-row cross-lane reduce).
// Pooling phase: lane = column block (coalesced), weights broadcast via LDS.
__global__ __launch_bounds__(256) void fused_lane_row(
    const float* __restrict__ x, const int* __restrict__ starts,
    const float* __restrict__ W, const float* __restrict__ b,
    const float* __restrict__ temp, float* __restrict__ scores_ws,
    float* __restrict__ xp, float* __restrict__ aw, int N, int G) {

    __shared__ float4 Wl[256];       // W as [h][d4]: Wl[h*64 + d4]  (4 KB)
    __shared__ float4 eb[NW][64];    // per-wave row-weight broadcast buffer (4 KB)

    const int t = threadIdx.x;
    Wl[t] = ((const float4*)W)[t];   // 256 threads x 1 float4 = full W
    __syncthreads();                 // only block-wide sync; waves independent after

    const int lane = t & 63;
    const int wid  = t >> 6;
    const int g = blockIdx.x * NW + wid;
    if (g >= G) return;

    const int s = starts[g];
    const int e = starts[g + 1];
    const int cnt = e - s;

    if (cnt == 0) {
        ((float4*)xp)[(size_t)g * 64 + lane] = make_float4(0.f, 0.f, 0.f, 0.f);
        return;
    }

    const float4* __restrict__ x4 = (const float4*)x;
    const float invT = 1.0f / temp[0];
    const float b0 = b[0], b1 = b[1], b2 = b[2], b3 = b[3];

    const int ngrp = (cnt + 63) >> 6;   // almost always 1 (mean cnt ~31)

    float m0 = -1e30f, m1 = -1e30f, m2 = -1e30f, m3 = -1e30f;
    float q0 = 0.f, q1 = 0.f, q2 = 0.f, q3 = 0.f;   // fast-path scores (lane's row)
    bool v0 = false;

    if (ngrp == 1) {
        const int r  = s + lane;
        v0 = (r < e);
        const int rc = v0 ? r : (e - 1);
        const float4* __restrict__ xr = x4 + (size_t)rc * 64;
        float t0 = 0.f, t1 = 0.f, t2 = 0.f, t3 = 0.f;
        #pragma unroll 4
        for (int d = 0; d < 64; ++d) {
            const float4 xv = xr[d];
            const float4 w0 = Wl[d], w1 = Wl[64 + d], w2 = Wl[128 + d], w3 = Wl[192 + d];
            t0 += xv.x*w0.x + xv.y*w0.y + xv.z*w0.z + xv.w*w0.w;
            t1 += xv.x*w1.x + xv.y*w1.y + xv.z*w1.z + xv.w*w1.w;
            t2 += xv.x*w2.x + xv.y*w2.y + xv.z*w2.z + xv.w*w2.w;
            t3 += xv.x*w3.x + xv.y*w3.y + xv.z*w3.z + xv.w*w3.w;
        }
        q0 = (t0 + b0) * invT; q1 = (t1 + b1) * invT;
        q2 = (t2 + b2) * invT; q3 = (t3 + b3) * invT;
        if (v0) { m0 = q0; m1 = q1; m2 = q2; m3 = q3; }
    } else {
        // rare path: multiple 64-row groups; scores round-trip via workspace
        for (int grp = 0; grp < ngrp; ++grp) {
            const int r  = s + grp * 64 + lane;
            const bool v = (r < e);
            const int rc = v ? r : (e - 1);
            const float4* __restrict__ xr = x4 + (size_t)rc * 64;
            float t0 = 0.f, t1 = 0.f, t2 = 0.f, t3 = 0.f;
            #pragma unroll 4
            for (int d = 0; d < 64; ++d) {
                const float4 xv = xr[d];
                const float4 w0 = Wl[d], w1 = Wl[64 + d], w2 = Wl[128 + d], w3 = Wl[192 + d];
                t0 += xv.x*w0.x + xv.y*w0.y + xv.z*w0.z + xv.w*w0.w;
                t1 += xv.x*w1.x + xv.y*w1.y + xv.z*w1.z + xv.w*w1.w;
                t2 += xv.x*w2.x + xv.y*w2.y + xv.z*w2.z + xv.w*w2.w;
                t3 += xv.x*w3.x + xv.y*w3.y + xv.z*w3.z + xv.w*w3.w;
            }
            const float s0 = (t0 + b0) * invT, s1 = (t1 + b1) * invT;
            const float s2 = (t2 + b2) * invT, s3 = (t3 + b3) * invT;
            if (v) {
                ((float4*)scores_ws)[r] = make_float4(s0, s1, s2, s3);
                m0 = fmaxf(m0, s0); m1 = fmaxf(m1, s1);
                m2 = fmaxf(m2, s2); m3 = fmaxf(m3, s3);
            }
        }
    }

    // per-graph butterfly max (once per graph, not per row)
    #pragma unroll
    for (int off = 32; off; off >>= 1) {
        m0 = fmaxf(m0, __shfl_xor(m0, off));
        m1 = fmaxf(m1, __shfl_xor(m1, off));
        m2 = fmaxf(m2, __shfl_xor(m2, off));
        m3 = fmaxf(m3, __shfl_xor(m3, off));
    }

    float l0 = 0.f, l1 = 0.f, l2 = 0.f, l3 = 0.f;
    float4 ac0 = make_float4(0.f,0.f,0.f,0.f), ac1 = ac0, ac2 = ac0, ac3 = ac0;
    float e0 = 0.f, e1 = 0.f, e2 = 0.f, e3 = 0.f;   // fast-path unnormalized weights

    if (ngrp == 1) {
        if (v0) {
            e0 = __expf(q0 - m0); e1 = __expf(q1 - m1);
            e2 = __expf(q2 - m2); e3 = __expf(q3 - m3);
        }
        l0 = e0; l1 = e1; l2 = e2; l3 = e3;
        eb[wid][lane] = make_float4(e0, e1, e2, e3);
        WAVE_LDS_FENCE();
        // pooling: lane = column block; rows re-read coalesced (L1/L2-hot)
        #pragma unroll 4
        for (int i = 0; i < cnt; ++i) {
            const float4 xv = x4[(size_t)(s + i) * 64 + lane];
            const float4 ee = eb[wid][i];   // lane-uniform broadcast
            ac0.x += ee.x*xv.x; ac0.y += ee.x*xv.y; ac0.z += ee.x*xv.z; ac0.w += ee.x*xv.w;
            ac1.x += ee.y*xv.x; ac1.y += ee.y*xv.y; ac1.z += ee.y*xv.z; ac1.w += ee.y*xv.w;
            ac2.x += ee.z*xv.x; ac2.y += ee.z*xv.y; ac2.z += ee.z*xv.z; ac2.w += ee.z*xv.w;
            ac3.x += ee.w*xv.x; ac3.y += ee.w*xv.y; ac3.z += ee.w*xv.z; ac3.w += ee.w*xv.w;
        }
    } else {
        WAVE_VM_FENCE();   // our scores_ws stores visible before same-wave readback
        for (int grp = 0; grp < ngrp; ++grp) {
            const int base = s + grp * 64;
            const int r = base + lane;
            const bool v = (r < e);
            const int rc = v ? r : (e - 1);
            const float4 sv = ((const float4*)scores_ws)[rc];
            float f0 = 0.f, f1 = 0.f, f2 = 0.f, f3 = 0.f;
            if (v) {
                f0 = __expf(sv.x - m0); f1 = __expf(sv.y - m1);
                f2 = __expf(sv.z - m2); f3 = __expf(sv.w - m3);
            }
            l0 += f0; l1 += f1; l2 += f2; l3 += f3;
            WAVE_LDS_FENCE();                 // previous group's reads complete
            eb[wid][lane] = make_float4(f0, f1, f2, f3);
            WAVE_LDS_FENCE();
            const int cs = min(64, e - base);
            for (int i = 0; i < cs; ++i) {
                const float4 xv = x4[(size_t)(base + i) * 64 + lane];
                const float4 ee = eb[wid][i];
                ac0.x += ee.x*xv.x; ac0.y += ee.x*xv.y; ac0.z += ee.x*xv.z; ac0.w += ee.x*xv.w;
                ac1.x += ee.y*xv.x; ac1.y += ee.y*xv.y; ac1.z += ee.y*xv.z; ac1.w += ee.y*xv.w;
                ac2.x += ee.z*xv.x; ac2.y += ee.z*xv.y; ac2.z += ee.z*xv.z; ac2.w += ee.z*xv.w;
                ac3.x += ee.w*xv.x; ac3.y += ee.w*xv.y; ac3.z += ee.w*xv.z; ac3.w += ee.w*xv.w;
            }
        }
    }

    // per-graph butterfly sum
    #pragma unroll
    for (int off = 32; off; off >>= 1) {
        l0 += __shfl_xor(l0, off);
        l1 += __shfl_xor(l1, off);
        l2 += __shfl_xor(l2, off);
        l3 += __shfl_xor(l3, off);
    }

    const float il0 = 1.f/l0, il1 = 1.f/l1, il2 = 1.f/l2, il3 = 1.f/l3;
    float4 out;
    out.x = 0.25f*(ac0.x*il0 + ac1.x*il1 + ac2.x*il2 + ac3.x*il3);
    out.y = 0.25f*(ac0.y*il0 + ac1.y*il1 + ac2.y*il2 + ac3.y*il3);
    out.z = 0.25f*(ac0.z*il0 + ac1.z*il1 + ac2.z*il2 + ac3.z*il3);
    out.w = 0.25f*(ac0.w*il0 + ac1.w*il1 + ac2.w*il2 + ac3.w*il3);
    ((float4*)xp)[(size_t)g * 64 + lane] = out;

    // attention weights [H, N]: lane = row, coalesced within graph range
    if (ngrp == 1) {
        if (v0) {
            const int r = s + lane;
            aw[0 * (size_t)N + r] = e0 * il0;
            aw[1 * (size_t)N + r] = e1 * il1;
            aw[2 * (size_t)N + r] = e2 * il2;
            aw[3 * (size_t)N + r] = e3 * il3;
        }
    } else {
        for (int grp = 0; grp < ngrp; ++grp) {
            const int r = s + grp * 64 + lane;
            if (r < e) {
                const float4 sv = ((const float4*)scores_ws)[r];
                aw[0 * (size_t)N + r] = __expf(sv.x - m0) * il0;
                aw[1 * (size_t)N + r] = __expf(sv.y - m1) * il1;
                aw[2 * (size_t)N + r] = __expf(sv.z - m2) * il2;
                aw[3 * (size_t)N + r] = __expf(sv.w - m3) * il3;
            }
        }
    }
}

extern "C" void kernel_launch(void* const* d_in, const int* in_sizes, int n_in,
                              void* d_out, int out_size, void* d_ws, size_t ws_size,
                              hipStream_t stream) {
    const float* x    = (const float*)d_in[0];
    const int*   bi   = (const int*)d_in[1];
    // d_in[2] = num_graphs (derived from out_size)
    const float* W    = (const float*)d_in[3];
    const float* b    = (const float*)d_in[4];
    const float* temp = (const float*)d_in[5];

    const int N = in_sizes[0] / DD;
    const int G = (out_size - HH * N) / DD;

    float* xp = (float*)d_out;                    // [G, D]
    float* aw = (float*)d_out + (size_t)G * DD;   // [H, N]

    float* scores_ws = (float*)d_ws;                               // N*H floats
    int*   starts    = (int*)((char*)d_ws + (size_t)N * HH * 4);   // G+1 ints

    starts_kernel<<<(G + 1 + 255) / 256, 256, 0, stream>>>(bi, starts, N, G);
    fused_lane_row<<<(G + NW - 1) / NW, 256, 0, stream>>>(
        x, starts, W, b, temp, scores_ws, xp, aw, N, G);
}